// Round 1
// baseline (3423.137 us; speedup 1.0000x reference)
//
#include <hip/hip_runtime.h>
#include <hip/hip_cooperative_groups.h>
#include <math.h>

namespace cg = cooperative_groups;

#define FD     512           // feature dim (W)
#define NBATCH 16            // bsz
#define TROWS  16            // rows per tile
#define NROWS  16384         // 16*8*128 rows total
#define NTILES (NROWS/TROWS) // 1024
#define TPB    256
#define MM     5
#define LAMV   1e-4f
#define MAXIT  50
#define TOLV   0.01f
#define NTOT   8388608       // 16*8*128*512
#define INIT_SLOT 48

// Persistent state in device globals (avoids any assumption about ws_size).
// Fully (re)initialized on every launch before use.
__device__ float g_Fm[MM][NTOT];          // F history slots
__device__ float g_G [MM][NTOT];          // G = F - X history slots
__device__ float g_xl[NTOT];              // last xnew (the answer pre-output-linear)
__device__ float g_Wt [FD*FD];            // lin_w transposed: Wt[k][c] = lin_w[c][k]
__device__ float g_WtO[FD*FD];            // weight transposed
__device__ float g_acc[INIT_SLOT+1][NBATCH][8]; // per-iteration Gram-row + den accumulators

static __device__ __forceinline__ void gemm_tile(const float* __restrict__ W,
                                                 const float* __restrict__ Asm,
                                                 const float* __restrict__ bvec,
                                                 int c0, int r0, float acc[8][4])
{
    float4 b4 = *(const float4*)(bvec + c0);
#pragma unroll
    for (int i = 0; i < 8; i++) { acc[i][0]=b4.x; acc[i][1]=b4.y; acc[i][2]=b4.z; acc[i][3]=b4.w; }
#pragma unroll 1
    for (int k = 0; k < FD; k += 4) {
        const float4 w0 = *(const float4*)(W + (k+0)*FD + c0);
        const float4 w1 = *(const float4*)(W + (k+1)*FD + c0);
        const float4 w2 = *(const float4*)(W + (k+2)*FD + c0);
        const float4 w3 = *(const float4*)(W + (k+3)*FD + c0);
#pragma unroll
        for (int i = 0; i < 8; i++) {
            const float4 av = *(const float4*)(Asm + (r0+i)*FD + k);
            acc[i][0] = fmaf(av.x, w0.x, acc[i][0]); acc[i][0] = fmaf(av.y, w1.x, acc[i][0]);
            acc[i][0] = fmaf(av.z, w2.x, acc[i][0]); acc[i][0] = fmaf(av.w, w3.x, acc[i][0]);
            acc[i][1] = fmaf(av.x, w0.y, acc[i][1]); acc[i][1] = fmaf(av.y, w1.y, acc[i][1]);
            acc[i][1] = fmaf(av.z, w2.y, acc[i][1]); acc[i][1] = fmaf(av.w, w3.y, acc[i][1]);
            acc[i][2] = fmaf(av.x, w0.z, acc[i][2]); acc[i][2] = fmaf(av.y, w1.z, acc[i][2]);
            acc[i][2] = fmaf(av.z, w2.z, acc[i][2]); acc[i][2] = fmaf(av.w, w3.z, acc[i][2]);
            acc[i][3] = fmaf(av.x, w0.w, acc[i][3]); acc[i][3] = fmaf(av.y, w1.w, acc[i][3]);
            acc[i][3] = fmaf(av.z, w2.w, acc[i][3]); acc[i][3] = fmaf(av.w, w3.w, acc[i][3]);
        }
    }
}

static __device__ __forceinline__ void red6(const float vals[6], float (*redS)[8], float* accrow)
{
    const int lane = threadIdx.x & 63, wv = threadIdx.x >> 6;
#pragma unroll
    for (int j = 0; j < 6; j++) {
        float v = vals[j];
#pragma unroll
        for (int o = 32; o; o >>= 1) v += __shfl_down(v, o);
        if (lane == 0) redS[wv][j] = v;
    }
    __syncthreads();
    if (threadIdx.x < 6) {
        const float s = redS[0][threadIdx.x] + redS[1][threadIdx.x]
                      + redS[2][threadIdx.x] + redS[3][threadIdx.x];
        atomicAdd(accrow + threadIdx.x, s);   // device-scope, cross-XCD coherent
    }
}

// LAPACK-style 6x6 LU with partial pivoting on the bordered Anderson system.
static __device__ __forceinline__ void solve_alpha(int b, int nk,
    float (*gramS)[MM][MM], float (*alphaS)[MM], float (*Hs)[44])
{
    float* H = Hs[b];  // 6 rows x 7 cols (augmented)
    for (int i = 0; i < 6; i++)
        for (int j = 0; j < 7; j++) H[i*7+j] = 0.f;
    for (int j = 0; j < nk; j++) { H[1+j] = 1.f; H[(1+j)*7] = 1.f; }
#pragma unroll
    for (int i = 0; i < MM; i++) H[(1+i)*7 + (1+i)] = LAMV;
    for (int i = 0; i < nk; i++)
        for (int j = 0; j < nk; j++)
            H[(1+i)*7 + (1+j)] = gramS[b][i][j] + (i == j ? LAMV : 0.f);
    H[6] = 1.f;  // rhs = e0
    for (int col = 0; col < 6; col++) {
        int p = col; float mx = fabsf(H[col*7+col]);
        for (int r2 = col+1; r2 < 6; r2++) {
            const float v = fabsf(H[r2*7+col]);
            if (v > mx) { mx = v; p = r2; }
        }
        if (p != col)
            for (int j = col; j < 7; j++) { const float t = H[col*7+j]; H[col*7+j] = H[p*7+j]; H[p*7+j] = t; }
        const float piv = H[col*7+col];
        for (int r2 = col+1; r2 < 6; r2++) {
            const float fct = H[r2*7+col] / piv;
            for (int j = col+1; j < 7; j++) H[r2*7+j] -= fct * H[col*7+j];
        }
    }
    for (int r2 = 5; r2 >= 0; r2--) {          // back-substitute into rhs column
        float s = H[r2*7+6];
        for (int j = r2+1; j < 6; j++) s -= H[r2*7+j] * H[j*7+6];
        H[r2*7+6] = s / H[r2*7+r2];
    }
#pragma unroll
    for (int m = 0; m < MM; m++) alphaS[b][m] = H[(1+m)*7+6];
}

__global__ void __launch_bounds__(TPB, 4)
aa_kernel(const float* __restrict__ x, const float* __restrict__ lin_w,
          const float* __restrict__ lin_b, const float* __restrict__ weight,
          const float* __restrict__ bias, float* __restrict__ out)
{
    cg::grid_group grid = cg::this_grid();
    __shared__ float As[TROWS*FD];            // 32 KB A-tile
    __shared__ float gramS[NBATCH][MM][MM];   // block-local persistent Gram copy
    __shared__ float alphaS[NBATCH][MM];
    __shared__ float Hs[NBATCH][44];
    __shared__ float redS[4][8];
    __shared__ float resS;

    const int tid  = threadIdx.x;
    const int nblk = gridDim.x;
    const int cg_  = tid & 127, rg_ = tid >> 7;
    const int c0 = cg_*4, r0 = rg_*8;

    // ---------- Phase A: transposes + zero accumulators ----------
    for (int i = blockIdx.x*TPB + tid; i < FD*FD; i += nblk*TPB) {
        const int k = i >> 9, c = i & (FD-1);
        g_Wt[i]  = lin_w[c*FD + k];
        g_WtO[i] = weight[c*FD + k];
    }
    {
        float* accf = &g_acc[0][0][0];
        for (int i = blockIdx.x*TPB + tid; i < (INIT_SLOT+1)*NBATCH*8; i += nblk*TPB)
            __hip_atomic_store(accf + i, 0.0f, __ATOMIC_RELAXED, __HIP_MEMORY_SCOPE_AGENT);
    }
    __threadfence();
    grid.sync();

    // ---------- Phase B: F0 = f(x0), F1 = f(F0), G0, G1, init Gram dots ----------
    for (int t = blockIdx.x; t < NTILES; t += nblk) {
        const int b = t >> 6;
        const int base = t * (TROWS*FD);
        __syncthreads();
#pragma unroll
        for (int i = 0; i < 8; i++) {
            const int q = tid + i*TPB;
            *(float4*)(&As[q*4]) = *(const float4*)(x + base + q*4);
        }
        __syncthreads();
        float acc[8][4];
        gemm_tile(g_Wt, As, lin_b, c0, r0, acc);
        float d00 = 0.f;
#pragma unroll
        for (int i = 0; i < 8; i++) {
            const int off = base + (r0+i)*FD + c0;
            const float4 xv = *(const float4*)(&As[(r0+i)*FD + c0]);
            float4 f; f.x=acc[i][0]; f.y=acc[i][1]; f.z=acc[i][2]; f.w=acc[i][3];
            float4 g; g.x=f.x-xv.x; g.y=f.y-xv.y; g.z=f.z-xv.z; g.w=f.w-xv.w;
            *(float4*)(&g_Fm[0][off]) = f;
            *(float4*)(&g_G [0][off]) = g;
            d00 = fmaf(g.x,g.x,d00); d00 = fmaf(g.y,g.y,d00);
            d00 = fmaf(g.z,g.z,d00); d00 = fmaf(g.w,g.w,d00);
        }
        __syncthreads();
#pragma unroll
        for (int i = 0; i < 8; i++) {   // F0 -> LDS for second GEMM
            float4 f; f.x=acc[i][0]; f.y=acc[i][1]; f.z=acc[i][2]; f.w=acc[i][3];
            *(float4*)(&As[(r0+i)*FD + c0]) = f;
        }
        __syncthreads();
        gemm_tile(g_Wt, As, lin_b, c0, r0, acc);
        float d01 = 0.f, d11 = 0.f;
#pragma unroll
        for (int i = 0; i < 8; i++) {
            const int off = base + (r0+i)*FD + c0;
            const float4 f0 = *(const float4*)(&As[(r0+i)*FD + c0]);
            float4 f; f.x=acc[i][0]; f.y=acc[i][1]; f.z=acc[i][2]; f.w=acc[i][3];
            float4 g; g.x=f.x-f0.x; g.y=f.y-f0.y; g.z=f.z-f0.z; g.w=f.w-f0.w;
            *(float4*)(&g_Fm[1][off]) = f;
            *(float4*)(&g_G [1][off]) = g;
            const float4 g0 = *(const float4*)(&g_G[0][off]);
            d01 = fmaf(g0.x,g.x,d01); d01 = fmaf(g0.y,g.y,d01);
            d01 = fmaf(g0.z,g.z,d01); d01 = fmaf(g0.w,g.w,d01);
            d11 = fmaf(g.x,g.x,d11); d11 = fmaf(g.y,g.y,d11);
            d11 = fmaf(g.z,g.z,d11); d11 = fmaf(g.w,g.w,d11);
        }
        const float vals[6] = {d00, d01, d11, 0.f, 0.f, 0.f};
        red6(vals, redS, &g_acc[INIT_SLOT][b][0]);
    }
    __threadfence();
    grid.sync();

    if (tid < NBATCH) {   // every block builds its own Gram copy from coherent acc
        const int b = tid;
        const float d00 = __hip_atomic_load(&g_acc[INIT_SLOT][b][0], __ATOMIC_RELAXED, __HIP_MEMORY_SCOPE_AGENT);
        const float d01 = __hip_atomic_load(&g_acc[INIT_SLOT][b][1], __ATOMIC_RELAXED, __HIP_MEMORY_SCOPE_AGENT);
        const float d11 = __hip_atomic_load(&g_acc[INIT_SLOT][b][2], __ATOMIC_RELAXED, __HIP_MEMORY_SCOPE_AGENT);
        gramS[b][0][0] = d00; gramS[b][0][1] = d01; gramS[b][1][0] = d01; gramS[b][1][1] = d11;
    }
    __syncthreads();

    // ---------- Main Anderson loop ----------
    for (int k = 2;; k++) {
        const int nk  = k < MM ? k : MM;
        const int idx = k % MM;
        const int it  = k - 2;

        if (tid < NBATCH) solve_alpha(tid, nk, gramS, alphaS, Hs);
        __syncthreads();

        for (int t = blockIdx.x; t < NTILES; t += nblk) {
            const int b = t >> 6;
            const int base = t * (TROWS*FD);
            __syncthreads();
            float al[MM];
#pragma unroll
            for (int m = 0; m < MM; m++) al[m] = alphaS[b][m];
            // pass 1: xnew = sum_m alpha_m * Fm[m]  -> LDS + xlast
#pragma unroll
            for (int i = 0; i < 8; i++) {
                const int q = tid + i*TPB;
                const int off = base + q*4;
                float4 v; v.x = v.y = v.z = v.w = 0.f;
                for (int m = 0; m < nk; m++) {
                    const float4 fm = *(const float4*)(&g_Fm[m][off]);
                    v.x = fmaf(al[m], fm.x, v.x); v.y = fmaf(al[m], fm.y, v.y);
                    v.z = fmaf(al[m], fm.z, v.z); v.w = fmaf(al[m], fm.w, v.w);
                }
                *(float4*)(&g_xl[off]) = v;
                *(float4*)(&As[q*4])   = v;
            }
            __syncthreads();
            // pass 2: fnew = xnew @ lin_w.T + lin_b
            float acc[8][4];
            gemm_tile(g_Wt, As, lin_b, c0, r0, acc);
            // pass 3: writes + Gram-row dots + residual partials
            float dv[6] = {0.f,0.f,0.f,0.f,0.f,0.f};
            float dself = 0.f;
#pragma unroll
            for (int i = 0; i < 8; i++) {
                const int off = base + (r0+i)*FD + c0;
                const float4 xv = *(const float4*)(&As[(r0+i)*FD + c0]);
                float4 f; f.x=acc[i][0]; f.y=acc[i][1]; f.z=acc[i][2]; f.w=acc[i][3];
                float4 g; g.x=f.x-xv.x; g.y=f.y-xv.y; g.z=f.z-xv.z; g.w=f.w-xv.w;
                *(float4*)(&g_Fm[idx][off]) = f;
                *(float4*)(&g_G [idx][off]) = g;
                dv[5] = fmaf(f.x,f.x,dv[5]); dv[5] = fmaf(f.y,f.y,dv[5]);
                dv[5] = fmaf(f.z,f.z,dv[5]); dv[5] = fmaf(f.w,f.w,dv[5]);
                dself = fmaf(g.x,g.x,dself); dself = fmaf(g.y,g.y,dself);
                dself = fmaf(g.z,g.z,dself); dself = fmaf(g.w,g.w,dself);
#pragma unroll
                for (int j = 0; j < MM; j++) {
                    if (j != idx && j < nk) {
                        const float4 gj = *(const float4*)(&g_G[j][off]);
                        dv[j] = fmaf(g.x,gj.x,dv[j]); dv[j] = fmaf(g.y,gj.y,dv[j]);
                        dv[j] = fmaf(g.z,gj.z,dv[j]); dv[j] = fmaf(g.w,gj.w,dv[j]);
                    }
                }
            }
            float vals[6];
#pragma unroll
            for (int j = 0; j < MM; j++) vals[j] = (j == idx) ? (dv[j] + dself) : dv[j];
            vals[5] = dv[5];
            red6(vals, redS, &g_acc[it][b][0]);
        }
        __threadfence();
        grid.sync();

        if (tid < NBATCH) {   // incremental Gram row/col update
            const int b = tid;
#pragma unroll
            for (int j = 0; j < MM; j++) {
                const float v = __hip_atomic_load(&g_acc[it][b][j], __ATOMIC_RELAXED, __HIP_MEMORY_SCOPE_AGENT);
                gramS[b][idx][j] = v;
                gramS[b][j][idx] = v;
            }
        }
        if (tid == 0) {
            float num = 0.f, den = 0.f;
            for (int b = 0; b < NBATCH; b++) {
                num += __hip_atomic_load(&g_acc[it][b][idx], __ATOMIC_RELAXED, __HIP_MEMORY_SCOPE_AGENT);
                den += __hip_atomic_load(&g_acc[it][b][5],   __ATOMIC_RELAXED, __HIP_MEMORY_SCOPE_AGENT);
            }
            resS = sqrtf(num) / (1e-5f + sqrtf(den));
        }
        __syncthreads();
        if (k + 1 >= MAXIT || resS < TOLV) break;   // uniform across all blocks
    }

    // ---------- Phase F: out = xlast @ weight.T + bias ----------
    for (int t = blockIdx.x; t < NTILES; t += nblk) {
        const int base = t * (TROWS*FD);
        __syncthreads();
#pragma unroll
        for (int i = 0; i < 8; i++) {
            const int q = tid + i*TPB;
            *(float4*)(&As[q*4]) = *(const float4*)(g_xl + base + q*4);
        }
        __syncthreads();
        float acc[8][4];
        gemm_tile(g_WtO, As, bias, c0, r0, acc);
#pragma unroll
        for (int i = 0; i < 8; i++) {
            const int off = base + (r0+i)*FD + c0;
            float4 f; f.x=acc[i][0]; f.y=acc[i][1]; f.z=acc[i][2]; f.w=acc[i][3];
            *(float4*)(out + off) = f;
        }
    }
}

extern "C" void kernel_launch(void* const* d_in, const int* in_sizes, int n_in,
                              void* d_out, int out_size, void* d_ws, size_t ws_size,
                              hipStream_t stream)
{
    (void)in_sizes; (void)n_in; (void)out_size; (void)d_ws; (void)ws_size;
    const float* x      = (const float*)d_in[0];
    const float* lin_w  = (const float*)d_in[1];
    const float* lin_b  = (const float*)d_in[2];
    const float* weight = (const float*)d_in[3];
    const float* bias   = (const float*)d_in[4];
    float* out = (float*)d_out;

    int dev = 0;
    hipGetDevice(&dev);
    hipDeviceProp_t prop;
    hipGetDeviceProperties(&prop, dev);
    int occ = 0;
    hipOccupancyMaxActiveBlocksPerMultiprocessor(&occ, aa_kernel, TPB, 0);
    if (occ < 1) occ = 1;
    int gridsz = occ * prop.multiProcessorCount;
    if (gridsz > NTILES) gridsz = NTILES;

    void* args[6];
    args[0] = (void*)&x;     args[1] = (void*)&lin_w; args[2] = (void*)&lin_b;
    args[3] = (void*)&weight; args[4] = (void*)&bias; args[5] = (void*)&out;
    hipLaunchCooperativeKernel(aa_kernel, dim3(gridsz), dim3(TPB), args, 0, stream);
}

// Round 3
// 1046.193 us; speedup vs baseline: 3.2720x; 3.2720x over previous
//
#include <hip/hip_runtime.h>
#include <math.h>

#define FD     512
#define NBATCH 16
#define NROWS  16384
#define NTILES 1024            // one 16-row tile per block
#define TPB    256
#define MM     5
#define LAMV   1e-4f
#define MAXIT  50
#define TOLV   0.01f
#define NTOT   8388608
#define PADW   520             // LDS row stride (bf16 elems), 16B aligned

typedef __attribute__((ext_vector_type(8))) short  short8;   // 8 bf16
typedef __attribute__((ext_vector_type(4))) float  float4v;  // MFMA C/D frag

// Persistent device state; fully rewritten (or provably unused) every call.
__device__ unsigned short g_Fm[MM][NTOT];
__device__ unsigned short g_G [MM][NTOT];
__device__ unsigned short g_xb[NTOT];
__device__ unsigned short g_Wb [FD*FD];        // bf16(lin_w) row-major
__device__ unsigned short g_WbO[FD*FD];        // bf16(weight) row-major
__device__ float g_acc [MAXIT-2][NBATCH][8];   // per-iteration Gram-row dots [0..4], ||f||^2 [5]
__device__ float g_acc0[NBATCH][8];            // init dots d00,d01,d11

static __device__ __forceinline__ unsigned short f2bf(float f) {
    unsigned u = __float_as_uint(f);
    u += 0x7fff + ((u >> 16) & 1);             // RNE
    return (unsigned short)(u >> 16);
}
static __device__ __forceinline__ float bf2f(unsigned short s) {
    return __uint_as_float(((unsigned)s) << 16);
}

// 16x512 tile GEMM: D = A(16x512 bf16, LDS) @ W^T + bias. W row-major bf16:
// lane for output col c reads W[c][k..k+7] as one 16B contiguous load.
// Layouts per verified m89/m91 mappings: A[m=lane&15][k=quad*8+j],
// B[k=quad*8+j][n=lane&15], C/D col=lane&15,row=quad*4+reg.
// MODE 0: bf16 -> FsOut (LDS). MODE 1: fp32 -> gout (global tile base).
template<int MODE>
static __device__ __forceinline__ void mfma_gemm(const unsigned short* __restrict__ Wb,
                                                 const float* __restrict__ bvec,
                                                 const unsigned short* AsIn,
                                                 unsigned short* FsOut,
                                                 float* __restrict__ gout)
{
    const int lane = threadIdx.x & 63;
    const int wv   = threadIdx.x >> 6;
    const int lm   = lane & 15;
    const int quad = lane >> 4;
    float4v acc[8];
#pragma unroll
    for (int ct = 0; ct < 8; ct++) {
        const float b = bvec[(wv*8+ct)*16 + lm];
        acc[ct][0]=b; acc[ct][1]=b; acc[ct][2]=b; acc[ct][3]=b;
    }
#pragma unroll
    for (int q = 0; q < 4; q++) {
        short8 af[4];
#pragma unroll
        for (int kb = 0; kb < 4; kb++)
            af[kb] = *(const short8*)(AsIn + lm*PADW + q*128 + kb*32 + quad*8);
#pragma unroll
        for (int ct = 0; ct < 8; ct++) {
            const unsigned short* bp = Wb + ((wv*8+ct)*16 + lm)*FD + q*128 + quad*8;
            const short8 b0 = *(const short8*)(bp);
            const short8 b1 = *(const short8*)(bp + 32);
            const short8 b2 = *(const short8*)(bp + 64);
            const short8 b3 = *(const short8*)(bp + 96);
            acc[ct] = __builtin_amdgcn_mfma_f32_16x16x32_bf16(af[0], b0, acc[ct], 0,0,0);
            acc[ct] = __builtin_amdgcn_mfma_f32_16x16x32_bf16(af[1], b1, acc[ct], 0,0,0);
            acc[ct] = __builtin_amdgcn_mfma_f32_16x16x32_bf16(af[2], b2, acc[ct], 0,0,0);
            acc[ct] = __builtin_amdgcn_mfma_f32_16x16x32_bf16(af[3], b3, acc[ct], 0,0,0);
        }
    }
#pragma unroll
    for (int ct = 0; ct < 8; ct++) {
        const int c = (wv*8+ct)*16 + lm;
#pragma unroll
        for (int r = 0; r < 4; r++) {
            const int row = quad*4 + r;
            if (MODE == 0) FsOut[row*PADW + c] = f2bf(acc[ct][r]);
            else           gout[row*FD + c]    = acc[ct][r];
        }
    }
}

static __device__ __forceinline__ void red6(const float vals[6], float (*redS)[8], float* accrow)
{
    const int lane = threadIdx.x & 63, wv = threadIdx.x >> 6;
#pragma unroll
    for (int j = 0; j < 6; j++) {
        float v = vals[j];
#pragma unroll
        for (int o = 32; o; o >>= 1) v += __shfl_down(v, o);
        if (lane == 0) redS[wv][j] = v;
    }
    __syncthreads();
    if (threadIdx.x < 6) {
        const float s = redS[0][threadIdx.x] + redS[1][threadIdx.x]
                      + redS[2][threadIdx.x] + redS[3][threadIdx.x];
        atomicAdd(accrow + threadIdx.x, s);   // device-scope
    }
}

// ---------------- init0: weight bf16 conversion + zero accumulators ----------
__global__ void __launch_bounds__(TPB) k_init0(const float* __restrict__ lin_w,
                                               const float* __restrict__ weight)
{
    const int i0 = blockIdx.x*TPB + threadIdx.x, stride = gridDim.x*TPB;
    for (int i = i0; i < FD*FD; i += stride) {
        g_Wb [i] = f2bf(lin_w[i]);
        g_WbO[i] = f2bf(weight[i]);
    }
    float* a = &g_acc[0][0][0];
    for (int i = i0; i < (MAXIT-2)*NBATCH*8; i += stride) a[i] = 0.f;
    float* a0 = &g_acc0[0][0];
    for (int i = i0; i < NBATCH*8; i += stride) a0[i] = 0.f;
}

// ---------------- init1: F0=f(x~0), F1=f(F~0), G0, G1, init Gram dots --------
__global__ void __launch_bounds__(TPB, 4) k_init1(const float* __restrict__ x,
                                                  const float* __restrict__ lin_b)
{
    __shared__ __align__(16) unsigned short As[16*PADW];
    __shared__ __align__(16) unsigned short Fs[16*PADW];
    __shared__ float redS[4][8];
    const int tid = threadIdx.x;
    const int t = blockIdx.x, b = t >> 6;
    const int base = t * (16*FD);

#pragma unroll
    for (int i = 0; i < 4; i++) {               // bf16(x0 tile) -> As
        const int e = (i*TPB + tid) * 8;
        const float4 a0 = *(const float4*)(x + base + e);
        const float4 a1 = *(const float4*)(x + base + e + 4);
        short8 v;
        v[0]=f2bf(a0.x); v[1]=f2bf(a0.y); v[2]=f2bf(a0.z); v[3]=f2bf(a0.w);
        v[4]=f2bf(a1.x); v[5]=f2bf(a1.y); v[6]=f2bf(a1.z); v[7]=f2bf(a1.w);
        *(short8*)(As + (e>>9)*PADW + (e&511)) = v;
    }
    __syncthreads();
    mfma_gemm<0>(g_Wb, lin_b, As, Fs, nullptr);   // Fs = bf16(f(x~0))
    __syncthreads();
    float d00 = 0.f;
#pragma unroll
    for (int i = 0; i < 4; i++) {
        const int e = (i*TPB + tid) * 8;
        const int off = base + e, lo = (e>>9)*PADW + (e&511);
        const short8 fv = *(const short8*)(Fs + lo);
        const short8 xv = *(const short8*)(As + lo);
        short8 gv;
#pragma unroll
        for (int j = 0; j < 8; j++) {
            const float g = bf2f((unsigned short)fv[j]) - bf2f((unsigned short)xv[j]);
            gv[j] = (short)f2bf(g);
            d00 = fmaf(g, g, d00);
        }
        *(short8*)(&g_Fm[0][off]) = fv;
        *(short8*)(&g_G [0][off]) = gv;
    }
    __syncthreads();
    mfma_gemm<0>(g_Wb, lin_b, Fs, As, nullptr);   // As = bf16(f(F~0))
    __syncthreads();
    float d01 = 0.f, d11 = 0.f;
#pragma unroll
    for (int i = 0; i < 4; i++) {
        const int e = (i*TPB + tid) * 8;
        const int off = base + e, lo = (e>>9)*PADW + (e&511);
        const short8 f1 = *(const short8*)(As + lo);
        const short8 f0 = *(const short8*)(Fs + lo);
        const short8 g0 = *(const short8*)(&g_G[0][off]);
        short8 gv;
#pragma unroll
        for (int j = 0; j < 8; j++) {
            const float g = bf2f((unsigned short)f1[j]) - bf2f((unsigned short)f0[j]);
            gv[j] = (short)f2bf(g);
            d11 = fmaf(g, g, d11);
            d01 = fmaf(bf2f((unsigned short)g0[j]), g, d01);
        }
        *(short8*)(&g_Fm[1][off]) = f1;
        *(short8*)(&g_G [1][off]) = gv;
    }
    const float vals[6] = {d00, d01, d11, 0.f, 0.f, 0.f};
    red6(vals, redS, &g_acc0[b][0]);
}

// ---------------- one Anderson iteration (k = 2..49) -------------------------
__global__ void __launch_bounds__(TPB, 4) k_iter(const float* __restrict__ lin_b, int k)
{
    __shared__ __align__(16) unsigned short As[16*PADW];
    __shared__ __align__(16) unsigned short Fs[16*PADW];
    __shared__ float gramS[MM][MM];
    __shared__ float alphaS[MM];
    __shared__ float Hs[48];
    __shared__ float redS[4][8];
    __shared__ float sres;

    const int tid = threadIdx.x;
    const int t = blockIdx.x, b = t >> 6;
    const int base = t * (16*FD);
    const int it = k - 2, idx = k % MM, nk = (k < MM) ? k : MM;

    // --- convergence check on res_{k-1}; skipped iterations leave zeros -> res 0
    if (k > 2) {
        float v = 0.f;
        if (tid < 32) {
            const int bb = tid & 15;
            const int jj = (tid < 16) ? ((k-1) % MM) : 5;
            v = g_acc[it-1][bb][jj];
        }
        v += __shfl_xor(v, 1); v += __shfl_xor(v, 2);
        v += __shfl_xor(v, 4); v += __shfl_xor(v, 8);
        const float num = __shfl(v, 0), den = __shfl(v, 16);
        if (tid == 0) sres = sqrtf(num) / (1e-5f + sqrtf(den));
    }
    __syncthreads();
    if (k > 2 && sres < TOLV) return;            // uniform across grid

    // --- Gram replay (chronological, last <=5 iterations) + bordered 6x6 solve
    if (tid == 0) {
#pragma unroll
        for (int i = 0; i < MM; i++)
#pragma unroll
            for (int j = 0; j < MM; j++) gramS[i][j] = 0.f;
        gramS[0][0] = g_acc0[b][0];
        gramS[0][1] = gramS[1][0] = g_acc0[b][1];
        gramS[1][1] = g_acc0[b][2];
        const int j0 = (k - 5 > 2) ? (k - 5) : 2;
        for (int j = j0; j < k; j++) {
            const int ij = j % MM, nkj = (j < MM) ? j : MM;
            for (int c = 0; c < MM; c++)
                if (c < nkj || c == ij) {
                    const float vv = g_acc[j-2][b][c];
                    gramS[ij][c] = vv; gramS[c][ij] = vv;
                }
        }
        float* H = Hs;                            // 6x7 augmented
        for (int i = 0; i < 42; i++) H[i] = 0.f;
        for (int j = 0; j < nk; j++) { H[1+j] = 1.f; H[(1+j)*7] = 1.f; }
#pragma unroll
        for (int i = 0; i < MM; i++) H[(1+i)*7 + (1+i)] = LAMV;
        for (int i = 0; i < nk; i++)
            for (int j = 0; j < nk; j++)
                H[(1+i)*7 + (1+j)] = gramS[i][j] + (i == j ? LAMV : 0.f);
        H[6] = 1.f;                               // rhs = e0
        for (int col = 0; col < 6; col++) {
            int p = col; float mx = fabsf(H[col*7+col]);
            for (int r2 = col+1; r2 < 6; r2++) {
                const float vv = fabsf(H[r2*7+col]);
                if (vv > mx) { mx = vv; p = r2; }
            }
            if (p != col)
                for (int j = col; j < 7; j++) { const float tt = H[col*7+j]; H[col*7+j] = H[p*7+j]; H[p*7+j] = tt; }
            const float piv = H[col*7+col];
            for (int r2 = col+1; r2 < 6; r2++) {
                const float fct = H[r2*7+col] / piv;
                for (int j = col+1; j < 7; j++) H[r2*7+j] -= fct * H[col*7+j];
            }
        }
        for (int r2 = 5; r2 >= 0; r2--) {
            float s = H[r2*7+6];
            for (int j = r2+1; j < 6; j++) s -= H[r2*7+j] * H[j*7+6];
            H[r2*7+6] = s / H[r2*7+r2];
        }
#pragma unroll
        for (int m = 0; m < MM; m++) alphaS[m] = H[(1+m)*7+6];
    }
    __syncthreads();

    float al[MM];
#pragma unroll
    for (int m = 0; m < MM; m++) al[m] = alphaS[m];

    // --- pass 1: x~ = bf16(sum_m alpha_m Fm[m]) -> As + g_xb
#pragma unroll
    for (int i = 0; i < 4; i++) {
        const int e = (i*TPB + tid) * 8;
        const int off = base + e;
        float s[8] = {0,0,0,0,0,0,0,0};
        for (int m = 0; m < nk; m++) {
            const short8 fm = *(const short8*)(&g_Fm[m][off]);
#pragma unroll
            for (int j = 0; j < 8; j++)
                s[j] = fmaf(al[m], bf2f((unsigned short)fm[j]), s[j]);
        }
        short8 v;
#pragma unroll
        for (int j = 0; j < 8; j++) v[j] = (short)f2bf(s[j]);
        *(short8*)(As + (e>>9)*PADW + (e&511)) = v;
        *(short8*)(&g_xb[off]) = v;
    }
    __syncthreads();
    // --- pass 2: Fs = bf16(x~ @ lin_w^T + lin_b)
    mfma_gemm<0>(g_Wb, lin_b, As, Fs, nullptr);
    __syncthreads();
    // --- pass 3: state writes + Gram-row dots + residual partials
    float dv[6] = {0,0,0,0,0,0};
    float dself = 0.f;
#pragma unroll
    for (int i = 0; i < 4; i++) {
        const int e = (i*TPB + tid) * 8;
        const int off = base + e, lo = (e>>9)*PADW + (e&511);
        const short8 fv = *(const short8*)(Fs + lo);
        const short8 xv = *(const short8*)(As + lo);
        float gg[8]; short8 gv;
#pragma unroll
        for (int j = 0; j < 8; j++) {
            const float ff = bf2f((unsigned short)fv[j]);
            const float g  = ff - bf2f((unsigned short)xv[j]);
            gg[j] = g; gv[j] = (short)f2bf(g);
            dv[5] = fmaf(ff, ff, dv[5]);
            dself = fmaf(g, g, dself);
        }
        *(short8*)(&g_Fm[idx][off]) = fv;
        *(short8*)(&g_G [idx][off]) = gv;
#pragma unroll
        for (int js = 0; js < MM; js++) {
            if (js != idx && js < nk) {
                const short8 gj = *(const short8*)(&g_G[js][off]);
#pragma unroll
                for (int j = 0; j < 8; j++)
                    dv[js] = fmaf(gg[j], bf2f((unsigned short)gj[j]), dv[js]);
            }
        }
    }
    float vals[6];
#pragma unroll
    for (int j = 0; j < MM; j++) vals[j] = (j == idx) ? (dv[j] + dself) : dv[j];
    vals[5] = dv[5];
    red6(vals, redS, &g_acc[it][b][0]);
}

// ---------------- final: out = x~last @ weight^T + bias (fp32) ---------------
__global__ void __launch_bounds__(TPB, 4) k_final(const float* __restrict__ bias,
                                                  float* __restrict__ out)
{
    __shared__ __align__(16) unsigned short As[16*PADW];
    const int tid = threadIdx.x;
    const int base = blockIdx.x * (16*FD);
#pragma unroll
    for (int i = 0; i < 4; i++) {
        const int e = (i*TPB + tid) * 8;
        *(short8*)(As + (e>>9)*PADW + (e&511)) = *(const short8*)(&g_xb[base + e]);
    }
    __syncthreads();
    mfma_gemm<1>(g_WbO, bias, As, nullptr, out + base);
}

extern "C" void kernel_launch(void* const* d_in, const int* in_sizes, int n_in,
                              void* d_out, int out_size, void* d_ws, size_t ws_size,
                              hipStream_t stream)
{
    (void)in_sizes; (void)n_in; (void)out_size; (void)d_ws; (void)ws_size;
    const float* x      = (const float*)d_in[0];
    const float* lin_w  = (const float*)d_in[1];
    const float* lin_b  = (const float*)d_in[2];
    const float* weight = (const float*)d_in[3];
    const float* bias   = (const float*)d_in[4];
    float* out = (float*)d_out;

    hipLaunchKernelGGL(k_init0, dim3(512),    dim3(TPB), 0, stream, lin_w, weight);
    hipLaunchKernelGGL(k_init1, dim3(NTILES), dim3(TPB), 0, stream, x, lin_b);
    for (int k = 2; k < MAXIT; k++)
        hipLaunchKernelGGL(k_iter, dim3(NTILES), dim3(TPB), 0, stream, lin_b, k);
    hipLaunchKernelGGL(k_final, dim3(NTILES), dim3(TPB), 0, stream, bias, out);
}

// Round 4
// 780.411 us; speedup vs baseline: 4.3863x; 1.3406x over previous
//
#include <hip/hip_runtime.h>
#include <math.h>

#define FD     512
#define NBATCH 16
#define NROWS  16384
#define ROWS   32              // rows per block
#define NBLK   (NROWS/ROWS)    // 512 blocks, 2/CU
#define TPB    256
#define MM     5
#define LAMV   1e-4f
#define MAXIT  50
#define TOLV   0.01f
#define NTOT   8388608
#define PADW   520             // LDS row stride (bf16 elems), 16B aligned

typedef __attribute__((ext_vector_type(8))) short  short8;   // 8 bf16
typedef __attribute__((ext_vector_type(4))) float  float4v;  // MFMA C/D frag

// Persistent device state; fully rewritten (or provably unused) every call.
__device__ unsigned short g_Fm[MM][NTOT];
__device__ unsigned short g_G [MM][NTOT];
__device__ unsigned short g_xb[NTOT];
__device__ unsigned short g_Wb [FD*FD];        // bf16(lin_w) row-major
__device__ unsigned short g_WbO[FD*FD];        // bf16(weight) row-major
__device__ float g_acc [MAXIT-2][NBATCH][8];   // per-iter Gram-row dots [0..4], ||f||^2 [5]
__device__ float g_acc0[NBATCH][8];            // init dots d00,d01,d11

static __device__ __forceinline__ unsigned short f2bf(float f) {
    unsigned u = __float_as_uint(f);
    u += 0x7fff + ((u >> 16) & 1);             // RNE
    return (unsigned short)(u >> 16);
}
static __device__ __forceinline__ float bf2f(unsigned short s) {
    return __uint_as_float(((unsigned)s) << 16);
}

// 32x512 tile GEMM: D = A(32x512 bf16, LDS) @ W^T + bias.
// Two 16-row MFMA tiles share every B fragment (2:1 MFMA:B-load).
// A[m=lane&15][k=quad*8+j], B[k=quad*8+j][n=lane&15], C/D col=lane&15,row=quad*4+reg.
// MODE 0: bf16 -> FsOut (LDS). MODE 1: fp32 -> gout (global tile base).
template<int MODE>
static __device__ __forceinline__ void mfma_gemm(const unsigned short* __restrict__ Wb,
                                                 const float* __restrict__ bvec,
                                                 const unsigned short* AsIn,
                                                 unsigned short* FsOut,
                                                 float* __restrict__ gout)
{
    const int lane = threadIdx.x & 63;
    const int wv   = threadIdx.x >> 6;
    const int lm   = lane & 15;
    const int quad = lane >> 4;
    float4v acc[2][8];
#pragma unroll
    for (int ct = 0; ct < 8; ct++) {
        const float b = bvec[(wv*8+ct)*16 + lm];
        acc[0][ct][0]=b; acc[0][ct][1]=b; acc[0][ct][2]=b; acc[0][ct][3]=b;
        acc[1][ct][0]=b; acc[1][ct][1]=b; acc[1][ct][2]=b; acc[1][ct][3]=b;
    }
#pragma unroll
    for (int q = 0; q < 4; q++) {
        short8 af[2][4];
#pragma unroll
        for (int r16 = 0; r16 < 2; r16++)
#pragma unroll
            for (int kb = 0; kb < 4; kb++)
                af[r16][kb] = *(const short8*)(AsIn + (r16*16 + lm)*PADW + q*128 + kb*32 + quad*8);
#pragma unroll
        for (int ct = 0; ct < 8; ct++) {
            const unsigned short* bp = Wb + ((wv*8+ct)*16 + lm)*FD + q*128 + quad*8;
            const short8 b0 = *(const short8*)(bp);
            const short8 b1 = *(const short8*)(bp + 32);
            const short8 b2 = *(const short8*)(bp + 64);
            const short8 b3 = *(const short8*)(bp + 96);
            acc[0][ct] = __builtin_amdgcn_mfma_f32_16x16x32_bf16(af[0][0], b0, acc[0][ct], 0,0,0);
            acc[1][ct] = __builtin_amdgcn_mfma_f32_16x16x32_bf16(af[1][0], b0, acc[1][ct], 0,0,0);
            acc[0][ct] = __builtin_amdgcn_mfma_f32_16x16x32_bf16(af[0][1], b1, acc[0][ct], 0,0,0);
            acc[1][ct] = __builtin_amdgcn_mfma_f32_16x16x32_bf16(af[1][1], b1, acc[1][ct], 0,0,0);
            acc[0][ct] = __builtin_amdgcn_mfma_f32_16x16x32_bf16(af[0][2], b2, acc[0][ct], 0,0,0);
            acc[1][ct] = __builtin_amdgcn_mfma_f32_16x16x32_bf16(af[1][2], b2, acc[1][ct], 0,0,0);
            acc[0][ct] = __builtin_amdgcn_mfma_f32_16x16x32_bf16(af[0][3], b3, acc[0][ct], 0,0,0);
            acc[1][ct] = __builtin_amdgcn_mfma_f32_16x16x32_bf16(af[1][3], b3, acc[1][ct], 0,0,0);
        }
    }
#pragma unroll
    for (int ct = 0; ct < 8; ct++) {
        const int c = (wv*8+ct)*16 + lm;
#pragma unroll
        for (int r16 = 0; r16 < 2; r16++)
#pragma unroll
            for (int r = 0; r < 4; r++) {
                const int row = r16*16 + quad*4 + r;
                if (MODE == 0) FsOut[row*PADW + c] = f2bf(acc[r16][ct][r]);
                else           gout[row*FD + c]    = acc[r16][ct][r];
            }
    }
}

static __device__ __forceinline__ void red6(const float vals[6], float (*redS)[8], float* accrow)
{
    const int lane = threadIdx.x & 63, wv = threadIdx.x >> 6;
#pragma unroll
    for (int j = 0; j < 6; j++) {
        float v = vals[j];
#pragma unroll
        for (int o = 32; o; o >>= 1) v += __shfl_down(v, o);
        if (lane == 0) redS[wv][j] = v;
    }
    __syncthreads();
    if (threadIdx.x < 6) {
        const float s = redS[0][threadIdx.x] + redS[1][threadIdx.x]
                      + redS[2][threadIdx.x] + redS[3][threadIdx.x];
        atomicAdd(accrow + threadIdx.x, s);   // device-scope
    }
}

// ---------------- init0: weight bf16 conversion + zero accumulators ----------
__global__ void __launch_bounds__(TPB) k_init0(const float* __restrict__ lin_w,
                                               const float* __restrict__ weight)
{
    const int i0 = blockIdx.x*TPB + threadIdx.x, stride = gridDim.x*TPB;
    for (int i = i0; i < FD*FD; i += stride) {
        g_Wb [i] = f2bf(lin_w[i]);
        g_WbO[i] = f2bf(weight[i]);
    }
    float* a = &g_acc[0][0][0];
    for (int i = i0; i < (MAXIT-2)*NBATCH*8; i += stride) a[i] = 0.f;
    float* a0 = &g_acc0[0][0];
    for (int i = i0; i < NBATCH*8; i += stride) a0[i] = 0.f;
}

// ---------------- init1: F0=f(x~0), F1=f(F~0), G0, G1, init Gram dots --------
__global__ void __launch_bounds__(TPB, 2) k_init1(const float* __restrict__ x,
                                                  const float* __restrict__ lin_b)
{
    __shared__ __align__(16) unsigned short As[ROWS*PADW];
    __shared__ __align__(16) unsigned short Fs[ROWS*PADW];
    __shared__ float redS[4][8];
    const int tid = threadIdx.x;
    const int t = blockIdx.x, b = t >> 5;
    const int base = t * (ROWS*FD);

#pragma unroll
    for (int i = 0; i < 8; i++) {               // bf16(x0 tile) -> As
        const int e = (i*TPB + tid) * 8;
        const float4 a0 = *(const float4*)(x + base + e);
        const float4 a1 = *(const float4*)(x + base + e + 4);
        short8 v;
        v[0]=f2bf(a0.x); v[1]=f2bf(a0.y); v[2]=f2bf(a0.z); v[3]=f2bf(a0.w);
        v[4]=f2bf(a1.x); v[5]=f2bf(a1.y); v[6]=f2bf(a1.z); v[7]=f2bf(a1.w);
        *(short8*)(As + (e>>9)*PADW + (e&511)) = v;
    }
    __syncthreads();
    mfma_gemm<0>(g_Wb, lin_b, As, Fs, nullptr);   // Fs = bf16(f(x~0))
    __syncthreads();
    float d00 = 0.f;
#pragma unroll
    for (int i = 0; i < 8; i++) {
        const int e = (i*TPB + tid) * 8;
        const int off = base + e, lo = (e>>9)*PADW + (e&511);
        const short8 fv = *(const short8*)(Fs + lo);
        const short8 xv = *(const short8*)(As + lo);
        short8 gv;
#pragma unroll
        for (int j = 0; j < 8; j++) {
            const float g = bf2f((unsigned short)fv[j]) - bf2f((unsigned short)xv[j]);
            gv[j] = (short)f2bf(g);
            d00 = fmaf(g, g, d00);
        }
        *(short8*)(&g_Fm[0][off]) = fv;
        *(short8*)(&g_G [0][off]) = gv;
    }
    __syncthreads();
    mfma_gemm<0>(g_Wb, lin_b, Fs, As, nullptr);   // As = bf16(f(F~0))
    __syncthreads();
    float d01 = 0.f, d11 = 0.f;
#pragma unroll
    for (int i = 0; i < 8; i++) {
        const int e = (i*TPB + tid) * 8;
        const int off = base + e, lo = (e>>9)*PADW + (e&511);
        const short8 f1 = *(const short8*)(As + lo);
        const short8 f0 = *(const short8*)(Fs + lo);
        const short8 g0 = *(const short8*)(&g_G[0][off]);
        short8 gv;
#pragma unroll
        for (int j = 0; j < 8; j++) {
            const float g = bf2f((unsigned short)f1[j]) - bf2f((unsigned short)f0[j]);
            gv[j] = (short)f2bf(g);
            d11 = fmaf(g, g, d11);
            d01 = fmaf(bf2f((unsigned short)g0[j]), g, d01);
        }
        *(short8*)(&g_Fm[1][off]) = f1;
        *(short8*)(&g_G [1][off]) = gv;
    }
    const float vals[6] = {d00, d01, d11, 0.f, 0.f, 0.f};
    red6(vals, redS, &g_acc0[b][0]);
}

// ---------------- one Anderson iteration (k = 2..49) -------------------------
__global__ void __launch_bounds__(TPB, 2) k_iter(const float* __restrict__ lin_b, int k)
{
    __shared__ __align__(16) unsigned short As[ROWS*PADW];
    __shared__ __align__(16) unsigned short Fs[ROWS*PADW];
    __shared__ float gramS[MM][MM];
    __shared__ float alphaS[MM];
    __shared__ float Hs[48];
    __shared__ float redS[4][8];
    __shared__ float sres;

    const int tid = threadIdx.x;
    const int t = blockIdx.x, b = t >> 5;
    const int base = t * (ROWS*FD);
    const int it = k - 2, idx = k % MM, nk = (k < MM) ? k : MM;

    // --- convergence check on res_{k-1}; skipped iterations leave zeros -> res 0
    if (k > 2) {
        float v = 0.f;
        if (tid < 32) {
            const int bb = tid & 15;
            const int jj = (tid < 16) ? ((k-1) % MM) : 5;
            v = g_acc[it-1][bb][jj];
        }
        v += __shfl_xor(v, 1); v += __shfl_xor(v, 2);
        v += __shfl_xor(v, 4); v += __shfl_xor(v, 8);
        const float num = __shfl(v, 0), den = __shfl(v, 16);
        if (tid == 0) sres = sqrtf(num) / (1e-5f + sqrtf(den));
    }
    __syncthreads();
    if (k > 2 && sres < TOLV) return;            // uniform across grid

    // --- Gram replay (chronological, last <=5 iterations) + bordered 6x6 solve
    if (tid == 0) {
#pragma unroll
        for (int i = 0; i < MM; i++)
#pragma unroll
            for (int j = 0; j < MM; j++) gramS[i][j] = 0.f;
        gramS[0][0] = g_acc0[b][0];
        gramS[0][1] = gramS[1][0] = g_acc0[b][1];
        gramS[1][1] = g_acc0[b][2];
        const int j0 = (k - 5 > 2) ? (k - 5) : 2;
        for (int j = j0; j < k; j++) {
            const int ij = j % MM, nkj = (j < MM) ? j : MM;
            for (int c = 0; c < MM; c++)
                if (c < nkj || c == ij) {
                    const float vv = g_acc[j-2][b][c];
                    gramS[ij][c] = vv; gramS[c][ij] = vv;
                }
        }
        float* H = Hs;                            // 6x7 augmented
        for (int i = 0; i < 42; i++) H[i] = 0.f;
        for (int j = 0; j < nk; j++) { H[1+j] = 1.f; H[(1+j)*7] = 1.f; }
#pragma unroll
        for (int i = 0; i < MM; i++) H[(1+i)*7 + (1+i)] = LAMV;
        for (int i = 0; i < nk; i++)
            for (int j = 0; j < nk; j++)
                H[(1+i)*7 + (1+j)] = gramS[i][j] + (i == j ? LAMV : 0.f);
        H[6] = 1.f;                               // rhs = e0
        for (int col = 0; col < 6; col++) {
            int p = col; float mx = fabsf(H[col*7+col]);
            for (int r2 = col+1; r2 < 6; r2++) {
                const float vv = fabsf(H[r2*7+col]);
                if (vv > mx) { mx = vv; p = r2; }
            }
            if (p != col)
                for (int j = col; j < 7; j++) { const float tt = H[col*7+j]; H[col*7+j] = H[p*7+j]; H[p*7+j] = tt; }
            const float piv = H[col*7+col];
            for (int r2 = col+1; r2 < 6; r2++) {
                const float fct = H[r2*7+col] / piv;
                for (int j = col+1; j < 7; j++) H[r2*7+j] -= fct * H[col*7+j];
            }
        }
        for (int r2 = 5; r2 >= 0; r2--) {
            float s = H[r2*7+6];
            for (int j = r2+1; j < 6; j++) s -= H[r2*7+j] * H[j*7+6];
            H[r2*7+6] = s / H[r2*7+r2];
        }
#pragma unroll
        for (int m = 0; m < MM; m++) alphaS[m] = H[(1+m)*7+6];
    }
    __syncthreads();

    float al[MM];
#pragma unroll
    for (int m = 0; m < MM; m++) al[m] = alphaS[m];

    // --- pass 1: x~ = bf16(sum_m alpha_m Fm[m]) -> As + g_xb
    if (nk == MM) {
#pragma unroll
        for (int i = 0; i < 8; i++) {
            const int e = (i*TPB + tid) * 8;
            const int off = base + e;
            float s[8] = {0,0,0,0,0,0,0,0};
#pragma unroll
            for (int m = 0; m < MM; m++) {
                const short8 fm = *(const short8*)(&g_Fm[m][off]);
#pragma unroll
                for (int j = 0; j < 8; j++)
                    s[j] = fmaf(al[m], bf2f((unsigned short)fm[j]), s[j]);
            }
            short8 v;
#pragma unroll
            for (int j = 0; j < 8; j++) v[j] = (short)f2bf(s[j]);
            *(short8*)(As + (e>>9)*PADW + (e&511)) = v;
            *(short8*)(&g_xb[off]) = v;
        }
    } else {
#pragma unroll
        for (int i = 0; i < 8; i++) {
            const int e = (i*TPB + tid) * 8;
            const int off = base + e;
            float s[8] = {0,0,0,0,0,0,0,0};
            for (int m = 0; m < nk; m++) {
                const short8 fm = *(const short8*)(&g_Fm[m][off]);
#pragma unroll
                for (int j = 0; j < 8; j++)
                    s[j] = fmaf(al[m], bf2f((unsigned short)fm[j]), s[j]);
            }
            short8 v;
#pragma unroll
            for (int j = 0; j < 8; j++) v[j] = (short)f2bf(s[j]);
            *(short8*)(As + (e>>9)*PADW + (e&511)) = v;
            *(short8*)(&g_xb[off]) = v;
        }
    }
    __syncthreads();
    // --- pass 2: Fs = bf16(x~ @ lin_w^T + lin_b)
    mfma_gemm<0>(g_Wb, lin_b, As, Fs, nullptr);
    __syncthreads();
    // --- pass 3: state writes + Gram-row dots + residual partials
    float dv[6] = {0,0,0,0,0,0};
    float dself = 0.f;
#pragma unroll
    for (int i = 0; i < 8; i++) {
        const int e = (i*TPB + tid) * 8;
        const int off = base + e, lo = (e>>9)*PADW + (e&511);
        const short8 fv = *(const short8*)(Fs + lo);
        const short8 xv = *(const short8*)(As + lo);
        float gg[8]; short8 gv;
#pragma unroll
        for (int j = 0; j < 8; j++) {
            const float ff = bf2f((unsigned short)fv[j]);
            const float g  = ff - bf2f((unsigned short)xv[j]);
            gg[j] = g; gv[j] = (short)f2bf(g);
            dv[5] = fmaf(ff, ff, dv[5]);
            dself = fmaf(g, g, dself);
        }
        *(short8*)(&g_Fm[idx][off]) = fv;
        *(short8*)(&g_G [idx][off]) = gv;
#pragma unroll
        for (int js = 0; js < MM; js++) {
            if (js != idx && js < nk) {
                const short8 gj = *(const short8*)(&g_G[js][off]);
#pragma unroll
                for (int j = 0; j < 8; j++)
                    dv[js] = fmaf(gg[j], bf2f((unsigned short)gj[j]), dv[js]);
            }
        }
    }
    float vals[6];
#pragma unroll
    for (int j = 0; j < MM; j++) vals[j] = (j == idx) ? (dv[j] + dself) : dv[j];
    vals[5] = dv[5];
    red6(vals, redS, &g_acc[it][b][0]);
}

// ---------------- final: out = x~last @ weight^T + bias (fp32) ---------------
__global__ void __launch_bounds__(TPB, 2) k_final(const float* __restrict__ bias,
                                                  float* __restrict__ out)
{
    __shared__ __align__(16) unsigned short As[ROWS*PADW];
    const int tid = threadIdx.x;
    const int base = blockIdx.x * (ROWS*FD);
#pragma unroll
    for (int i = 0; i < 8; i++) {
        const int e = (i*TPB + tid) * 8;
        *(short8*)(As + (e>>9)*PADW + (e&511)) = *(const short8*)(&g_xb[base + e]);
    }
    __syncthreads();
    mfma_gemm<1>(g_WbO, bias, As, nullptr, out + base);
}

extern "C" void kernel_launch(void* const* d_in, const int* in_sizes, int n_in,
                              void* d_out, int out_size, void* d_ws, size_t ws_size,
                              hipStream_t stream)
{
    (void)in_sizes; (void)n_in; (void)out_size; (void)d_ws; (void)ws_size;
    const float* x      = (const float*)d_in[0];
    const float* lin_w  = (const float*)d_in[1];
    const float* lin_b  = (const float*)d_in[2];
    const float* weight = (const float*)d_in[3];
    const float* bias   = (const float*)d_in[4];
    float* out = (float*)d_out;

    hipLaunchKernelGGL(k_init0, dim3(512),  dim3(TPB), 0, stream, lin_w, weight);
    hipLaunchKernelGGL(k_init1, dim3(NBLK), dim3(TPB), 0, stream, x, lin_b);
    for (int k = 2; k < MAXIT; k++)
        hipLaunchKernelGGL(k_iter, dim3(NBLK), dim3(TPB), 0, stream, lin_b, k);
    hipLaunchKernelGGL(k_final, dim3(NBLK), dim3(TPB), 0, stream, bias, out);
}

// Round 5
// 732.264 us; speedup vs baseline: 4.6747x; 1.0658x over previous
//
#include <hip/hip_runtime.h>
#include <math.h>

#define FD     512
#define NBATCH 16
#define NROWS  16384
#define ROWS   32              // rows per block
#define NBLK   (NROWS/ROWS)    // 512 blocks, 2/CU (LDS-limited)
#define TPB    512             // 8 waves/block -> 16 waves/CU
#define MM     5
#define LAMV   1e-4f
#define MAXIT  50
#define TOLV   0.01f
#define NTOT   8388608
#define PADW   520             // LDS row stride (bf16 elems), 16B aligned

typedef __attribute__((ext_vector_type(8))) short  short8;   // 8 bf16
typedef __attribute__((ext_vector_type(4))) float  float4v;  // MFMA C/D frag

// Persistent device state; fully rewritten (or provably unused) every call.
__device__ unsigned short g_Fm[MM][NTOT];
__device__ unsigned short g_G [MM][NTOT];
__device__ unsigned short g_xb[NTOT];
__device__ unsigned short g_Wb [FD*FD];        // bf16(lin_w) row-major
__device__ unsigned short g_WbO[FD*FD];        // bf16(weight) row-major
__device__ float g_acc [MAXIT-2][NBATCH][8];   // per-iter Gram-row dots [0..4], ||f||^2 [5]
__device__ float g_acc0[NBATCH][8];            // init dots d00,d01,d11

static __device__ __forceinline__ unsigned short f2bf(float f) {
    unsigned u = __float_as_uint(f);
    u += 0x7fff + ((u >> 16) & 1);             // RNE
    return (unsigned short)(u >> 16);
}
static __device__ __forceinline__ float bf2f(unsigned short s) {
    return __uint_as_float(((unsigned)s) << 16);
}

// 32x512 tile GEMM: D = A(32x512 bf16, LDS) @ W^T + bias.
// 8 waves; each wave owns 64 output cols (4 ct-tiles), two 16-row tiles share
// every B fragment (2:1 MFMA:B-load). A[m=lane&15][k=quad*8+j],
// B[k=quad*8+j][n=lane&15], C/D col=lane&15,row=quad*4+reg (verified m89/m91).
// MODE 0: bf16 -> FsOut (LDS). MODE 1: fp32 -> gout (global tile base).
template<int MODE>
static __device__ __forceinline__ void mfma_gemm(const unsigned short* __restrict__ Wb,
                                                 const float* __restrict__ bvec,
                                                 const unsigned short* AsIn,
                                                 unsigned short* FsOut,
                                                 float* __restrict__ gout)
{
    const int lane = threadIdx.x & 63;
    const int wv   = threadIdx.x >> 6;     // 0..7
    const int lm   = lane & 15;
    const int quad = lane >> 4;
    float4v acc[2][4];
#pragma unroll
    for (int ct = 0; ct < 4; ct++) {
        const float b = bvec[(wv*4+ct)*16 + lm];
        acc[0][ct][0]=b; acc[0][ct][1]=b; acc[0][ct][2]=b; acc[0][ct][3]=b;
        acc[1][ct][0]=b; acc[1][ct][1]=b; acc[1][ct][2]=b; acc[1][ct][3]=b;
    }
#pragma unroll
    for (int q = 0; q < 4; q++) {
        short8 af[2][4];
#pragma unroll
        for (int r16 = 0; r16 < 2; r16++)
#pragma unroll
            for (int kb = 0; kb < 4; kb++)
                af[r16][kb] = *(const short8*)(AsIn + (r16*16 + lm)*PADW + q*128 + kb*32 + quad*8);
#pragma unroll
        for (int ct = 0; ct < 4; ct++) {
            const unsigned short* bp = Wb + ((wv*4+ct)*16 + lm)*FD + q*128 + quad*8;
            const short8 b0 = *(const short8*)(bp);
            const short8 b1 = *(const short8*)(bp + 32);
            const short8 b2 = *(const short8*)(bp + 64);
            const short8 b3 = *(const short8*)(bp + 96);
            acc[0][ct] = __builtin_amdgcn_mfma_f32_16x16x32_bf16(af[0][0], b0, acc[0][ct], 0,0,0);
            acc[1][ct] = __builtin_amdgcn_mfma_f32_16x16x32_bf16(af[1][0], b0, acc[1][ct], 0,0,0);
            acc[0][ct] = __builtin_amdgcn_mfma_f32_16x16x32_bf16(af[0][1], b1, acc[0][ct], 0,0,0);
            acc[1][ct] = __builtin_amdgcn_mfma_f32_16x16x32_bf16(af[1][1], b1, acc[1][ct], 0,0,0);
            acc[0][ct] = __builtin_amdgcn_mfma_f32_16x16x32_bf16(af[0][2], b2, acc[0][ct], 0,0,0);
            acc[1][ct] = __builtin_amdgcn_mfma_f32_16x16x32_bf16(af[1][2], b2, acc[1][ct], 0,0,0);
            acc[0][ct] = __builtin_amdgcn_mfma_f32_16x16x32_bf16(af[0][3], b3, acc[0][ct], 0,0,0);
            acc[1][ct] = __builtin_amdgcn_mfma_f32_16x16x32_bf16(af[1][3], b3, acc[1][ct], 0,0,0);
        }
    }
#pragma unroll
    for (int ct = 0; ct < 4; ct++) {
        const int c = (wv*4+ct)*16 + lm;
#pragma unroll
        for (int r16 = 0; r16 < 2; r16++)
#pragma unroll
            for (int r = 0; r < 4; r++) {
                const int row = r16*16 + quad*4 + r;
                if (MODE == 0) FsOut[row*PADW + c] = f2bf(acc[r16][ct][r]);
                else           gout[row*FD + c]    = acc[r16][ct][r];
            }
    }
}

static __device__ __forceinline__ void red6(const float vals[6], float (*redS)[8], float* accrow)
{
    const int lane = threadIdx.x & 63, wv = threadIdx.x >> 6;   // wv 0..7
#pragma unroll
    for (int j = 0; j < 6; j++) {
        float v = vals[j];
#pragma unroll
        for (int o = 32; o; o >>= 1) v += __shfl_down(v, o);
        if (lane == 0) redS[wv][j] = v;
    }
    __syncthreads();
    if (threadIdx.x < 6) {
        float s = 0.f;
#pragma unroll
        for (int w = 0; w < 8; w++) s += redS[w][threadIdx.x];
        atomicAdd(accrow + threadIdx.x, s);   // device-scope
    }
}

// ---------------- init0: weight bf16 conversion + zero accumulators ----------
__global__ void __launch_bounds__(256) k_init0(const float* __restrict__ lin_w,
                                               const float* __restrict__ weight)
{
    const int i0 = blockIdx.x*256 + threadIdx.x, stride = gridDim.x*256;
    for (int i = i0; i < FD*FD; i += stride) {
        g_Wb [i] = f2bf(lin_w[i]);
        g_WbO[i] = f2bf(weight[i]);
    }
    float* a = &g_acc[0][0][0];
    for (int i = i0; i < (MAXIT-2)*NBATCH*8; i += stride) a[i] = 0.f;
    float* a0 = &g_acc0[0][0];
    for (int i = i0; i < NBATCH*8; i += stride) a0[i] = 0.f;
}

// ---------------- init1: F0=f(x~0), F1=f(F~0), G0, G1, init Gram dots --------
__global__ void __launch_bounds__(TPB, 4) k_init1(const float* __restrict__ x,
                                                  const float* __restrict__ lin_b)
{
    __shared__ __align__(16) unsigned short As[ROWS*PADW];
    __shared__ __align__(16) unsigned short Fs[ROWS*PADW];
    __shared__ float redS[8][8];
    const int tid = threadIdx.x;
    const int t = blockIdx.x, b = t >> 5;
    const int base = t * (ROWS*FD);

#pragma unroll
    for (int i = 0; i < 4; i++) {               // bf16(x0 tile) -> As
        const int e = (i*TPB + tid) * 8;
        const float4 a0 = *(const float4*)(x + base + e);
        const float4 a1 = *(const float4*)(x + base + e + 4);
        short8 v;
        v[0]=f2bf(a0.x); v[1]=f2bf(a0.y); v[2]=f2bf(a0.z); v[3]=f2bf(a0.w);
        v[4]=f2bf(a1.x); v[5]=f2bf(a1.y); v[6]=f2bf(a1.z); v[7]=f2bf(a1.w);
        *(short8*)(As + (e>>9)*PADW + (e&511)) = v;
    }
    __syncthreads();
    mfma_gemm<0>(g_Wb, lin_b, As, Fs, nullptr);   // Fs = bf16(f(x~0))
    __syncthreads();
    float d00 = 0.f;
#pragma unroll
    for (int i = 0; i < 4; i++) {
        const int e = (i*TPB + tid) * 8;
        const int off = base + e, lo = (e>>9)*PADW + (e&511);
        const short8 fv = *(const short8*)(Fs + lo);
        const short8 xv = *(const short8*)(As + lo);
        short8 gv;
#pragma unroll
        for (int j = 0; j < 8; j++) {
            const float g = bf2f((unsigned short)fv[j]) - bf2f((unsigned short)xv[j]);
            gv[j] = (short)f2bf(g);
            d00 = fmaf(g, g, d00);
        }
        *(short8*)(&g_Fm[0][off]) = fv;
        *(short8*)(&g_G [0][off]) = gv;
    }
    __syncthreads();
    mfma_gemm<0>(g_Wb, lin_b, Fs, As, nullptr);   // As = bf16(f(F~0))
    __syncthreads();
    float d01 = 0.f, d11 = 0.f;
#pragma unroll
    for (int i = 0; i < 4; i++) {
        const int e = (i*TPB + tid) * 8;
        const int off = base + e, lo = (e>>9)*PADW + (e&511);
        const short8 f1 = *(const short8*)(As + lo);
        const short8 f0 = *(const short8*)(Fs + lo);
        const short8 g0 = *(const short8*)(&g_G[0][off]);
        short8 gv;
#pragma unroll
        for (int j = 0; j < 8; j++) {
            const float g = bf2f((unsigned short)f1[j]) - bf2f((unsigned short)f0[j]);
            gv[j] = (short)f2bf(g);
            d11 = fmaf(g, g, d11);
            d01 = fmaf(bf2f((unsigned short)g0[j]), g, d01);
        }
        *(short8*)(&g_Fm[1][off]) = f1;
        *(short8*)(&g_G [1][off]) = gv;
    }
    const float vals[6] = {d00, d01, d11, 0.f, 0.f, 0.f};
    red6(vals, redS, &g_acc0[b][0]);
}

// ---------------- one Anderson iteration (k = 2..49) -------------------------
__global__ void __launch_bounds__(TPB, 4) k_iter(const float* __restrict__ lin_b, int k)
{
    __shared__ __align__(16) unsigned short As[ROWS*PADW];
    __shared__ __align__(16) unsigned short Fs[ROWS*PADW];
    __shared__ float gramS[MM][MM];
    __shared__ float alphaS[MM];
    __shared__ float Hs[48];
    __shared__ float redS[8][8];
    __shared__ float sres;

    const int tid = threadIdx.x;
    const int t = blockIdx.x, b = t >> 5;
    const int base = t * (ROWS*FD);
    const int it = k - 2, idx = k % MM, nk = (k < MM) ? k : MM;

    // --- convergence check on res_{k-1}; skipped iterations leave zeros -> res 0
    if (k > 2) {
        float v = 0.f;
        if (tid < 32) {
            const int bb = tid & 15;
            const int jj = (tid < 16) ? ((k-1) % MM) : 5;
            v = g_acc[it-1][bb][jj];
        }
        v += __shfl_xor(v, 1); v += __shfl_xor(v, 2);
        v += __shfl_xor(v, 4); v += __shfl_xor(v, 8);
        const float num = __shfl(v, 0), den = __shfl(v, 16);
        if (tid == 0) sres = sqrtf(num) / (1e-5f + sqrtf(den));
    }
    __syncthreads();
    if (k > 2 && sres < TOLV) return;            // uniform across grid

    // --- Gram replay (chronological, last <=5 iterations) + bordered 6x6 solve
    if (tid == 0) {
#pragma unroll
        for (int i = 0; i < MM; i++)
#pragma unroll
            for (int j = 0; j < MM; j++) gramS[i][j] = 0.f;
        gramS[0][0] = g_acc0[b][0];
        gramS[0][1] = gramS[1][0] = g_acc0[b][1];
        gramS[1][1] = g_acc0[b][2];
        const int j0 = (k - 5 > 2) ? (k - 5) : 2;
        for (int j = j0; j < k; j++) {
            const int ij = j % MM, nkj = (j < MM) ? j : MM;
            for (int c = 0; c < MM; c++)
                if (c < nkj || c == ij) {
                    const float vv = g_acc[j-2][b][c];
                    gramS[ij][c] = vv; gramS[c][ij] = vv;
                }
        }
        float* H = Hs;                            // 6x7 augmented
        for (int i = 0; i < 42; i++) H[i] = 0.f;
        for (int j = 0; j < nk; j++) { H[1+j] = 1.f; H[(1+j)*7] = 1.f; }
#pragma unroll
        for (int i = 0; i < MM; i++) H[(1+i)*7 + (1+i)] = LAMV;
        for (int i = 0; i < nk; i++)
            for (int j = 0; j < nk; j++)
                H[(1+i)*7 + (1+j)] = gramS[i][j] + (i == j ? LAMV : 0.f);
        H[6] = 1.f;                               // rhs = e0
        for (int col = 0; col < 6; col++) {
            int p = col; float mx = fabsf(H[col*7+col]);
            for (int r2 = col+1; r2 < 6; r2++) {
                const float vv = fabsf(H[r2*7+col]);
                if (vv > mx) { mx = vv; p = r2; }
            }
            if (p != col)
                for (int j = col; j < 7; j++) { const float tt = H[col*7+j]; H[col*7+j] = H[p*7+j]; H[p*7+j] = tt; }
            const float piv = H[col*7+col];
            for (int r2 = col+1; r2 < 6; r2++) {
                const float fct = H[r2*7+col] / piv;
                for (int j = col+1; j < 7; j++) H[r2*7+j] -= fct * H[col*7+j];
            }
        }
        for (int r2 = 5; r2 >= 0; r2--) {
            float s = H[r2*7+6];
            for (int j = r2+1; j < 6; j++) s -= H[r2*7+j] * H[j*7+6];
            H[r2*7+6] = s / H[r2*7+r2];
        }
#pragma unroll
        for (int m = 0; m < MM; m++) alphaS[m] = H[(1+m)*7+6];
    }
    __syncthreads();

    float al[MM];
#pragma unroll
    for (int m = 0; m < MM; m++) al[m] = alphaS[m];

    // --- pass 1: x~ = bf16(sum_m alpha_m Fm[m]) -> As + g_xb
    if (nk == MM) {
#pragma unroll
        for (int i = 0; i < 4; i++) {
            const int e = (i*TPB + tid) * 8;
            const int off = base + e;
            float s[8] = {0,0,0,0,0,0,0,0};
#pragma unroll
            for (int m = 0; m < MM; m++) {
                const short8 fm = *(const short8*)(&g_Fm[m][off]);
#pragma unroll
                for (int j = 0; j < 8; j++)
                    s[j] = fmaf(al[m], bf2f((unsigned short)fm[j]), s[j]);
            }
            short8 v;
#pragma unroll
            for (int j = 0; j < 8; j++) v[j] = (short)f2bf(s[j]);
            *(short8*)(As + (e>>9)*PADW + (e&511)) = v;
            *(short8*)(&g_xb[off]) = v;
        }
    } else {
#pragma unroll
        for (int i = 0; i < 4; i++) {
            const int e = (i*TPB + tid) * 8;
            const int off = base + e;
            float s[8] = {0,0,0,0,0,0,0,0};
            for (int m = 0; m < nk; m++) {
                const short8 fm = *(const short8*)(&g_Fm[m][off]);
#pragma unroll
                for (int j = 0; j < 8; j++)
                    s[j] = fmaf(al[m], bf2f((unsigned short)fm[j]), s[j]);
            }
            short8 v;
#pragma unroll
            for (int j = 0; j < 8; j++) v[j] = (short)f2bf(s[j]);
            *(short8*)(As + (e>>9)*PADW + (e&511)) = v;
            *(short8*)(&g_xb[off]) = v;
        }
    }
    __syncthreads();
    // --- pass 2: Fs = bf16(x~ @ lin_w^T + lin_b)
    mfma_gemm<0>(g_Wb, lin_b, As, Fs, nullptr);
    __syncthreads();
    // --- pass 3: state writes + Gram-row dots + residual partials
    float dv[6] = {0,0,0,0,0,0};
    float dself = 0.f;
#pragma unroll
    for (int i = 0; i < 4; i++) {
        const int e = (i*TPB + tid) * 8;
        const int off = base + e, lo = (e>>9)*PADW + (e&511);
        const short8 fv = *(const short8*)(Fs + lo);
        const short8 xv = *(const short8*)(As + lo);
        float gg[8]; short8 gv;
#pragma unroll
        for (int j = 0; j < 8; j++) {
            const float ff = bf2f((unsigned short)fv[j]);
            const float g  = ff - bf2f((unsigned short)xv[j]);
            gg[j] = g; gv[j] = (short)f2bf(g);
            dv[5] = fmaf(ff, ff, dv[5]);
            dself = fmaf(g, g, dself);
        }
        *(short8*)(&g_Fm[idx][off]) = fv;
        *(short8*)(&g_G [idx][off]) = gv;
#pragma unroll
        for (int js = 0; js < MM; js++) {
            if (js != idx && js < nk) {
                const short8 gj = *(const short8*)(&g_G[js][off]);
#pragma unroll
                for (int j = 0; j < 8; j++)
                    dv[js] = fmaf(gg[j], bf2f((unsigned short)gj[j]), dv[js]);
            }
        }
    }
    float vals[6];
#pragma unroll
    for (int j = 0; j < MM; j++) vals[j] = (j == idx) ? (dv[j] + dself) : dv[j];
    vals[5] = dv[5];
    red6(vals, redS, &g_acc[it][b][0]);
}

// ---------------- final: out = x~last @ weight^T + bias (fp32) ---------------
__global__ void __launch_bounds__(TPB, 4) k_final(const float* __restrict__ bias,
                                                  float* __restrict__ out)
{
    __shared__ __align__(16) unsigned short As[ROWS*PADW];
    const int tid = threadIdx.x;
    const int base = blockIdx.x * (ROWS*FD);
#pragma unroll
    for (int i = 0; i < 4; i++) {
        const int e = (i*TPB + tid) * 8;
        *(short8*)(As + (e>>9)*PADW + (e&511)) = *(const short8*)(&g_xb[base + e]);
    }
    __syncthreads();
    mfma_gemm<1>(g_WbO, bias, As, nullptr, out + base);
}

extern "C" void kernel_launch(void* const* d_in, const int* in_sizes, int n_in,
                              void* d_out, int out_size, void* d_ws, size_t ws_size,
                              hipStream_t stream)
{
    (void)in_sizes; (void)n_in; (void)out_size; (void)d_ws; (void)ws_size;
    const float* x      = (const float*)d_in[0];
    const float* lin_w  = (const float*)d_in[1];
    const float* lin_b  = (const float*)d_in[2];
    const float* weight = (const float*)d_in[3];
    const float* bias   = (const float*)d_in[4];
    float* out = (float*)d_out;

    hipLaunchKernelGGL(k_init0, dim3(512),  dim3(256), 0, stream, lin_w, weight);
    hipLaunchKernelGGL(k_init1, dim3(NBLK), dim3(TPB), 0, stream, x, lin_b);
    for (int k = 2; k < MAXIT; k++)
        hipLaunchKernelGGL(k_iter, dim3(NBLK), dim3(TPB), 0, stream, lin_b, k);
    hipLaunchKernelGGL(k_final, dim3(NBLK), dim3(TPB), 0, stream, bias, out);
}

// Round 6
// 630.013 us; speedup vs baseline: 5.4334x; 1.1623x over previous
//
#include <hip/hip_runtime.h>
#include <math.h>

#define FD     512
#define NBATCH 16
#define NROWS  16384
#define ROWS   64              // rows per block
#define NBLK   (NROWS/ROWS)    // 256 blocks = 1 per CU
#define TPB    1024            // 16 waves/block
#define MM     5
#define LAMV   1e-4f
#define MAXIT  50
#define TOLV   0.01f
#define NTOT   8388608
#define PADW   520             // LDS row stride (bf16 elems), 16B aligned

typedef __attribute__((ext_vector_type(8))) short  short8;   // 8 bf16
typedef __attribute__((ext_vector_type(4))) float  float4v;  // MFMA C/D frag

// Persistent device state; fully rewritten (or provably unused) every call.
__device__ unsigned short g_Fm[MM][NTOT];
__device__ unsigned short g_G [MM][NTOT];
__device__ unsigned short g_xb[NTOT];
__device__ unsigned short g_Wb [FD*FD];        // bf16(lin_w) row-major
__device__ unsigned short g_WbO[FD*FD];        // bf16(weight) row-major
__device__ float g_acc [MAXIT-2][NBATCH][8];   // per-iter Gram-row dots [0..4], ||f||^2 [5]
__device__ float g_acc0[NBATCH][8];            // init dots d00,d01,d11

static __device__ __forceinline__ unsigned short f2bf(float f) {
    unsigned u = __float_as_uint(f);
    u += 0x7fff + ((u >> 16) & 1);             // RNE
    return (unsigned short)(u >> 16);
}
static __device__ __forceinline__ float bf2f(unsigned short s) {
    return __uint_as_float(((unsigned)s) << 16);
}

// 64x512 tile GEMM: D = A(64x512 bf16, LDS) @ W^T + bias.
// 16 waves; wave owns 32 output cols (2 ct) x all 64 rows (4 r16) -> each B
// fragment feeds 4 MFMAs (4:1 reuse), halving L2 B-traffic vs 32-row blocks.
// A[m=lane&15][k=quad*8+j], B[k=quad*8+j][n=lane&15], C/D col=lane&15,
// row=quad*4+reg (verified m89/m91 layouts).
// MODE 0: bf16 -> FsOut (LDS). MODE 1: fp32 -> gout (global tile base).
template<int MODE>
static __device__ __forceinline__ void mfma_gemm(const unsigned short* __restrict__ Wb,
                                                 const float* __restrict__ bvec,
                                                 const unsigned short* AsIn,
                                                 unsigned short* FsOut,
                                                 float* __restrict__ gout)
{
    const int lane = threadIdx.x & 63;
    const int wv   = threadIdx.x >> 6;     // 0..15
    const int lm   = lane & 15;
    const int quad = lane >> 4;
    float4v acc[4][2];
#pragma unroll
    for (int ct = 0; ct < 2; ct++) {
        const float b = bvec[wv*32 + ct*16 + lm];
#pragma unroll
        for (int r16 = 0; r16 < 4; r16++) {
            acc[r16][ct][0]=b; acc[r16][ct][1]=b; acc[r16][ct][2]=b; acc[r16][ct][3]=b;
        }
    }
#pragma unroll
    for (int q = 0; q < 4; q++) {
#pragma unroll
        for (int kb = 0; kb < 4; kb++) {
            const int ko = q*128 + kb*32 + quad*8;
            short8 bf[2];
#pragma unroll
            for (int ct = 0; ct < 2; ct++)
                bf[ct] = *(const short8*)(Wb + (wv*32 + ct*16 + lm)*FD + ko);
            short8 af[4];
#pragma unroll
            for (int r16 = 0; r16 < 4; r16++)
                af[r16] = *(const short8*)(AsIn + (r16*16 + lm)*PADW + ko);
#pragma unroll
            for (int r16 = 0; r16 < 4; r16++) {
                acc[r16][0] = __builtin_amdgcn_mfma_f32_16x16x32_bf16(af[r16], bf[0], acc[r16][0], 0,0,0);
                acc[r16][1] = __builtin_amdgcn_mfma_f32_16x16x32_bf16(af[r16], bf[1], acc[r16][1], 0,0,0);
            }
        }
    }
#pragma unroll
    for (int ct = 0; ct < 2; ct++) {
        const int c = wv*32 + ct*16 + lm;
#pragma unroll
        for (int r16 = 0; r16 < 4; r16++)
#pragma unroll
            for (int r = 0; r < 4; r++) {
                const int row = r16*16 + quad*4 + r;
                if (MODE == 0) FsOut[row*PADW + c] = f2bf(acc[r16][ct][r]);
                else           gout[row*FD + c]    = acc[r16][ct][r];
            }
    }
}

static __device__ __forceinline__ void red6(const float vals[6], float (*redS)[8], float* accrow)
{
    const int lane = threadIdx.x & 63, wv = threadIdx.x >> 6;   // wv 0..15
#pragma unroll
    for (int j = 0; j < 6; j++) {
        float v = vals[j];
#pragma unroll
        for (int o = 32; o; o >>= 1) v += __shfl_down(v, o);
        if (lane == 0) redS[wv][j] = v;
    }
    __syncthreads();
    if (threadIdx.x < 6) {
        float s = 0.f;
#pragma unroll
        for (int w = 0; w < 16; w++) s += redS[w][threadIdx.x];
        atomicAdd(accrow + threadIdx.x, s);   // device-scope
    }
}

// ---------------- init0: weight bf16 conversion + zero accumulators ----------
__global__ void __launch_bounds__(256) k_init0(const float* __restrict__ lin_w,
                                               const float* __restrict__ weight)
{
    const int i0 = blockIdx.x*256 + threadIdx.x, stride = gridDim.x*256;
    for (int i = i0; i < FD*FD; i += stride) {
        g_Wb [i] = f2bf(lin_w[i]);
        g_WbO[i] = f2bf(weight[i]);
    }
    float* a = &g_acc[0][0][0];
    for (int i = i0; i < (MAXIT-2)*NBATCH*8; i += stride) a[i] = 0.f;
    float* a0 = &g_acc0[0][0];
    for (int i = i0; i < NBATCH*8; i += stride) a0[i] = 0.f;
}

// ---------------- init1: F0=f(x~0), F1=f(F~0), G0, G1, init Gram dots --------
__global__ void __launch_bounds__(TPB, 4) k_init1(const float* __restrict__ x,
                                                  const float* __restrict__ lin_b)
{
    __shared__ __align__(16) unsigned short As[ROWS*PADW];
    __shared__ __align__(16) unsigned short Fs[ROWS*PADW];
    __shared__ float redS[16][8];
    const int tid = threadIdx.x;
    const int t = blockIdx.x, b = t >> 4;
    const int base = t * (ROWS*FD);

#pragma unroll
    for (int i = 0; i < 4; i++) {               // bf16(x0 tile) -> As
        const int e = (i*TPB + tid) * 8;
        const float4 a0 = *(const float4*)(x + base + e);
        const float4 a1 = *(const float4*)(x + base + e + 4);
        short8 v;
        v[0]=f2bf(a0.x); v[1]=f2bf(a0.y); v[2]=f2bf(a0.z); v[3]=f2bf(a0.w);
        v[4]=f2bf(a1.x); v[5]=f2bf(a1.y); v[6]=f2bf(a1.z); v[7]=f2bf(a1.w);
        *(short8*)(As + (e>>9)*PADW + (e&511)) = v;
    }
    __syncthreads();
    mfma_gemm<0>(g_Wb, lin_b, As, Fs, nullptr);   // Fs = bf16(f(x~0))
    __syncthreads();
    float d00 = 0.f;
#pragma unroll
    for (int i = 0; i < 4; i++) {
        const int e = (i*TPB + tid) * 8;
        const int off = base + e, lo = (e>>9)*PADW + (e&511);
        const short8 fv = *(const short8*)(Fs + lo);
        const short8 xv = *(const short8*)(As + lo);
        short8 gv;
#pragma unroll
        for (int j = 0; j < 8; j++) {
            const float g = bf2f((unsigned short)fv[j]) - bf2f((unsigned short)xv[j]);
            gv[j] = (short)f2bf(g);
            d00 = fmaf(g, g, d00);
        }
        *(short8*)(&g_Fm[0][off]) = fv;
        *(short8*)(&g_G [0][off]) = gv;
    }
    __syncthreads();
    mfma_gemm<0>(g_Wb, lin_b, Fs, As, nullptr);   // As = bf16(f(F~0))
    __syncthreads();
    float d01 = 0.f, d11 = 0.f;
#pragma unroll
    for (int i = 0; i < 4; i++) {
        const int e = (i*TPB + tid) * 8;
        const int off = base + e, lo = (e>>9)*PADW + (e&511);
        const short8 f1 = *(const short8*)(As + lo);
        const short8 f0 = *(const short8*)(Fs + lo);
        const short8 g0 = *(const short8*)(&g_G[0][off]);
        short8 gv;
#pragma unroll
        for (int j = 0; j < 8; j++) {
            const float g = bf2f((unsigned short)f1[j]) - bf2f((unsigned short)f0[j]);
            gv[j] = (short)f2bf(g);
            d11 = fmaf(g, g, d11);
            d01 = fmaf(bf2f((unsigned short)g0[j]), g, d01);
        }
        *(short8*)(&g_Fm[1][off]) = f1;
        *(short8*)(&g_G [1][off]) = gv;
    }
    const float vals[6] = {d00, d01, d11, 0.f, 0.f, 0.f};
    red6(vals, redS, &g_acc0[b][0]);
}

// ---------------- one Anderson iteration (k = 2..49) -------------------------
__global__ void __launch_bounds__(TPB, 4) k_iter(const float* __restrict__ lin_b, int k)
{
    __shared__ __align__(16) unsigned short As[ROWS*PADW];
    __shared__ __align__(16) unsigned short Fs[ROWS*PADW];
    __shared__ float gramS[MM][MM];
    __shared__ float alphaS[MM];
    __shared__ float Hs[48];
    __shared__ float redS[16][8];
    __shared__ float sres;

    const int tid = threadIdx.x;
    const int t = blockIdx.x, b = t >> 4;
    const int base = t * (ROWS*FD);
    const int it = k - 2, idx = k % MM, nk = (k < MM) ? k : MM;

    // --- convergence check on res_{k-1}; skipped iterations leave zeros -> res 0
    if (k > 2) {
        float v = 0.f;
        if (tid < 32) {
            const int bb = tid & 15;
            const int jj = (tid < 16) ? ((k-1) % MM) : 5;
            v = g_acc[it-1][bb][jj];
        }
        v += __shfl_xor(v, 1); v += __shfl_xor(v, 2);
        v += __shfl_xor(v, 4); v += __shfl_xor(v, 8);
        const float num = __shfl(v, 0), den = __shfl(v, 16);
        if (tid == 0) sres = sqrtf(num) / (1e-5f + sqrtf(den));
    }
    __syncthreads();
    if (k > 2 && sres < TOLV) return;            // uniform across grid

    // --- Gram replay (chronological, last <=5 iterations) + bordered 6x6 solve
    if (tid == 0) {
#pragma unroll
        for (int i = 0; i < MM; i++)
#pragma unroll
            for (int j = 0; j < MM; j++) gramS[i][j] = 0.f;
        gramS[0][0] = g_acc0[b][0];
        gramS[0][1] = gramS[1][0] = g_acc0[b][1];
        gramS[1][1] = g_acc0[b][2];
        const int j0 = (k - 5 > 2) ? (k - 5) : 2;
        for (int j = j0; j < k; j++) {
            const int ij = j % MM, nkj = (j < MM) ? j : MM;
            for (int c = 0; c < MM; c++)
                if (c < nkj || c == ij) {
                    const float vv = g_acc[j-2][b][c];
                    gramS[ij][c] = vv; gramS[c][ij] = vv;
                }
        }
        float* H = Hs;                            // 6x7 augmented
        for (int i = 0; i < 42; i++) H[i] = 0.f;
        for (int j = 0; j < nk; j++) { H[1+j] = 1.f; H[(1+j)*7] = 1.f; }
#pragma unroll
        for (int i = 0; i < MM; i++) H[(1+i)*7 + (1+i)] = LAMV;
        for (int i = 0; i < nk; i++)
            for (int j = 0; j < nk; j++)
                H[(1+i)*7 + (1+j)] = gramS[i][j] + (i == j ? LAMV : 0.f);
        H[6] = 1.f;                               // rhs = e0
        for (int col = 0; col < 6; col++) {
            int p = col; float mx = fabsf(H[col*7+col]);
            for (int r2 = col+1; r2 < 6; r2++) {
                const float vv = fabsf(H[r2*7+col]);
                if (vv > mx) { mx = vv; p = r2; }
            }
            if (p != col)
                for (int j = col; j < 7; j++) { const float tt = H[col*7+j]; H[col*7+j] = H[p*7+j]; H[p*7+j] = tt; }
            const float piv = H[col*7+col];
            for (int r2 = col+1; r2 < 6; r2++) {
                const float fct = H[r2*7+col] / piv;
                for (int j = col+1; j < 7; j++) H[r2*7+j] -= fct * H[col*7+j];
            }
        }
        for (int r2 = 5; r2 >= 0; r2--) {
            float s = H[r2*7+6];
            for (int j = r2+1; j < 6; j++) s -= H[r2*7+j] * H[j*7+6];
            H[r2*7+6] = s / H[r2*7+r2];
        }
#pragma unroll
        for (int m = 0; m < MM; m++) alphaS[m] = H[(1+m)*7+6];
    }
    __syncthreads();

    float al[MM];
#pragma unroll
    for (int m = 0; m < MM; m++) al[m] = alphaS[m];

    // --- pass 1: x~ = bf16(sum_m alpha_m Fm[m]) -> As + g_xb
    if (nk == MM) {
#pragma unroll
        for (int i = 0; i < 4; i++) {
            const int e = (i*TPB + tid) * 8;
            const int off = base + e;
            float s[8] = {0,0,0,0,0,0,0,0};
#pragma unroll
            for (int m = 0; m < MM; m++) {
                const short8 fm = *(const short8*)(&g_Fm[m][off]);
#pragma unroll
                for (int j = 0; j < 8; j++)
                    s[j] = fmaf(al[m], bf2f((unsigned short)fm[j]), s[j]);
            }
            short8 v;
#pragma unroll
            for (int j = 0; j < 8; j++) v[j] = (short)f2bf(s[j]);
            *(short8*)(As + (e>>9)*PADW + (e&511)) = v;
            *(short8*)(&g_xb[off]) = v;
        }
    } else {
#pragma unroll
        for (int i = 0; i < 4; i++) {
            const int e = (i*TPB + tid) * 8;
            const int off = base + e;
            float s[8] = {0,0,0,0,0,0,0,0};
            for (int m = 0; m < nk; m++) {
                const short8 fm = *(const short8*)(&g_Fm[m][off]);
#pragma unroll
                for (int j = 0; j < 8; j++)
                    s[j] = fmaf(al[m], bf2f((unsigned short)fm[j]), s[j]);
            }
            short8 v;
#pragma unroll
            for (int j = 0; j < 8; j++) v[j] = (short)f2bf(s[j]);
            *(short8*)(As + (e>>9)*PADW + (e&511)) = v;
            *(short8*)(&g_xb[off]) = v;
        }
    }
    __syncthreads();
    // --- pass 2: Fs = bf16(x~ @ lin_w^T + lin_b)
    mfma_gemm<0>(g_Wb, lin_b, As, Fs, nullptr);
    __syncthreads();
    // --- pass 3: state writes + Gram-row dots + residual partials
    float dv[6] = {0,0,0,0,0,0};
    float dself = 0.f;
#pragma unroll
    for (int i = 0; i < 4; i++) {
        const int e = (i*TPB + tid) * 8;
        const int off = base + e, lo = (e>>9)*PADW + (e&511);
        const short8 fv = *(const short8*)(Fs + lo);
        const short8 xv = *(const short8*)(As + lo);
        float gg[8]; short8 gv;
#pragma unroll
        for (int j = 0; j < 8; j++) {
            const float ff = bf2f((unsigned short)fv[j]);
            const float g  = ff - bf2f((unsigned short)xv[j]);
            gg[j] = g; gv[j] = (short)f2bf(g);
            dv[5] = fmaf(ff, ff, dv[5]);
            dself = fmaf(g, g, dself);
        }
        *(short8*)(&g_Fm[idx][off]) = fv;
        *(short8*)(&g_G [idx][off]) = gv;
#pragma unroll
        for (int js = 0; js < MM; js++) {
            if (js != idx && js < nk) {
                const short8 gj = *(const short8*)(&g_G[js][off]);
#pragma unroll
                for (int j = 0; j < 8; j++)
                    dv[js] = fmaf(gg[j], bf2f((unsigned short)gj[j]), dv[js]);
            }
        }
    }
    float vals[6];
#pragma unroll
    for (int j = 0; j < MM; j++) vals[j] = (j == idx) ? (dv[j] + dself) : dv[j];
    vals[5] = dv[5];
    red6(vals, redS, &g_acc[it][b][0]);
}

// ---------------- final: out = x~last @ weight^T + bias (fp32) ---------------
__global__ void __launch_bounds__(TPB, 4) k_final(const float* __restrict__ bias,
                                                  float* __restrict__ out)
{
    __shared__ __align__(16) unsigned short As[ROWS*PADW];
    const int tid = threadIdx.x;
    const int base = blockIdx.x * (ROWS*FD);
#pragma unroll
    for (int i = 0; i < 4; i++) {
        const int e = (i*TPB + tid) * 8;
        *(short8*)(As + (e>>9)*PADW + (e&511)) = *(const short8*)(&g_xb[base + e]);
    }
    __syncthreads();
    mfma_gemm<1>(g_WbO, bias, As, nullptr, out + base);
}

extern "C" void kernel_launch(void* const* d_in, const int* in_sizes, int n_in,
                              void* d_out, int out_size, void* d_ws, size_t ws_size,
                              hipStream_t stream)
{
    (void)in_sizes; (void)n_in; (void)out_size; (void)d_ws; (void)ws_size;
    const float* x      = (const float*)d_in[0];
    const float* lin_w  = (const float*)d_in[1];
    const float* lin_b  = (const float*)d_in[2];
    const float* weight = (const float*)d_in[3];
    const float* bias   = (const float*)d_in[4];
    float* out = (float*)d_out;

    hipLaunchKernelGGL(k_init0, dim3(512),  dim3(256), 0, stream, lin_w, weight);
    hipLaunchKernelGGL(k_init1, dim3(NBLK), dim3(TPB), 0, stream, x, lin_b);
    for (int k = 2; k < MAXIT; k++)
        hipLaunchKernelGGL(k_iter, dim3(NBLK), dim3(TPB), 0, stream, lin_b, k);
    hipLaunchKernelGGL(k_final, dim3(NBLK), dim3(TPB), 0, stream, bias, out);
}